// Round 19
// baseline (358.408 us; speedup 1.0000x reference)
//
#include <hip/hip_runtime.h>
#include <hip/hip_bf16.h>
#include <stdint.h>

typedef unsigned short u16;
typedef __attribute__((ext_vector_type(8))) short short8;
typedef __attribute__((ext_vector_type(4))) float float4v;
typedef __attribute__((ext_vector_type(4))) unsigned int uint4v;

#define B_    2
#define N_    2048
#define DIM_  1024
#define H_    16
#define DH_   64
#define DI_   1024
#define EPS_  1.1920928955078125e-07f
#define LOG2_THETA 13.287712379549449f
#define SCL_  0.18033688011112042f   // (1/sqrt(64)) * log2(e)

__device__ __forceinline__ float bf2f(u16 u) {
    union { unsigned int i; float f; } v; v.i = ((unsigned int)u) << 16; return v.f;
}
__device__ __forceinline__ u16 f2bf(float f) {
    union { float f; unsigned int i; } v; v.f = f;
    unsigned int r = v.i + 0x7fff + ((v.i >> 16) & 1);
    return (u16)(r >> 16);
}
// single-instruction packed f32->bf16 (RNE)
__device__ __forceinline__ unsigned int cvtpk(float a, float b) {
    unsigned int r;
    asm("v_cvt_pk_bf16_f32 %0, %1, %2" : "=v"(r) : "v"(a), "v"(b));
    return r;
}
// key permutation within a 32-key group (matches S^T reg layout -> B-operand)
__device__ __forceinline__ int perm32(int n) {
    return (n & ~31) + (((n >> 2) & 3) * 8) + (((n >> 4) & 1) * 4) + (n & 3);
}

// ---------------- merged preprocessing: qkv weight transpose + token RMSNorm ----------------
__global__ __launch_bounds__(256) void k_pre(
    const float* __restrict__ w_q, const float* __restrict__ w_k,
    const float* __restrict__ w_v, u16* __restrict__ dstW,
    const float* __restrict__ tok, const float* __restrict__ w_norm,
    u16* __restrict__ xn) {
    int bx = blockIdx.x;
    int t = threadIdx.x;
    __shared__ float tile[32][33];
    __shared__ float red[4];
    if (bx < 7168) {
        // ---- transpose_qkv tile (c-tile = bx%224, k-tile = bx/224) ----
        int c0 = (bx % 224) * 32, k0 = (bx / 224) * 32;
        const float* src; int sN, sc0;
        if (c0 < 1024)      { src = w_q; sN = 1024; sc0 = c0; }
        else if (c0 < 4096) { src = w_k; sN = 3072; sc0 = c0 - 1024; }
        else                { src = w_v; sN = 3072; sc0 = c0 - 4096; }
        int tx = t & 31, ty = t >> 5;
#pragma unroll
        for (int i = 0; i < 4; ++i)
            tile[ty + 8 * i][tx] = src[(size_t)(k0 + ty + 8 * i) * sN + sc0 + tx];
        __syncthreads();
#pragma unroll
        for (int i = 0; i < 4; ++i)
            dstW[(size_t)(c0 + ty + 8 * i) * 1024 + k0 + tx] = f2bf(tile[tx][ty + 8 * i]);
    } else {
        // ---- rmsnorm_x row = bx - 7168 (vectorized) ----
        int row = bx - 7168;
        const float* tr = tok + (size_t)row * DIM_ + t * 4;
        float4v v = *(const float4v*)tr;
        float ss = v[0] * v[0] + v[1] * v[1] + v[2] * v[2] + v[3] * v[3];
#pragma unroll
        for (int o = 32; o; o >>= 1) ss += __shfl_xor(ss, o, 64);
        if ((t & 63) == 0) red[t >> 6] = ss;
        __syncthreads();
        ss = red[0] + red[1] + red[2] + red[3];
        float rs = rsqrtf(ss * (1.0f / DIM_) + EPS_);
        const float* wp = w_norm + t * 4;
        uint2 pk;
        pk.x = cvtpk(v[0] * rs * wp[0], v[1] * rs * wp[1]);
        pk.y = cvtpk(v[2] * rs * wp[2], v[3] * rs * wp[3]);
        *(uint2*)(xn + (size_t)row * DIM_ + t * 4) = pk;
    }
}

// ---------------- single weight transpose (K x N fp32) -> (N x K bf16) ----------------
__global__ __launch_bounds__(256) void k_transpose(
    const float* __restrict__ src, u16* __restrict__ dst, int K, int N) {
    __shared__ float tile[32][33];
    int n0 = blockIdx.x * 32, k0 = blockIdx.y * 32;
    int tx = threadIdx.x, ty = threadIdx.y;  // 32 x 8
#pragma unroll
    for (int i = 0; i < 4; ++i)
        tile[ty + 8 * i][tx] = src[(size_t)(k0 + ty + 8 * i) * N + n0 + tx];
    __syncthreads();
#pragma unroll
    for (int i = 0; i < 4; ++i)
        dst[(size_t)(n0 + ty + 8 * i) * K + k0 + tx] = f2bf(tile[tx][ty + 8 * i]);
}

// ------- merged post-GEMM: V transpose + K rms+rope (independent col ranges) -------
__global__ __launch_bounds__(256) void k_post1(
    u16* __restrict__ QKVB, u16* __restrict__ Vt, const float* __restrict__ w) {
    int bx = blockIdx.x;
    int t = threadIdx.x;
    __shared__ u16 tile[64][72];
    if (bx < 3072) {
        // ---- transpose_v (vectorized): y = bx>>5, n-tile = bx&31 ----
        int y = bx >> 5;
        int s = y >> 5;
        int b = (y >> 4) & 1;
        int h = y & 15;
        int n0 = (bx & 31) * 64;
#pragma unroll
        for (int i = 0; i < 2; ++i) {
            int idx = i * 256 + t;
            int row = idx >> 3, c = idx & 7;
            uint4v v = *(const uint4v*)(QKVB + ((size_t)(b * N_) + n0 + row) * 7168
                                            + 4096 + s * 1024 + h * 64 + c * 8);
            *(uint4v*)&tile[row][c * 8] = v;
        }
        __syncthreads();
        u16* out = Vt + (size_t)y * 64 * N_;
#pragma unroll
        for (int i = 0; i < 2; ++i) {
            int idx = i * 256 + t;
            int dh = idx >> 3, og = idx & 7;
            u16 vals[8];
#pragma unroll
            for (int j = 0; j < 8; ++j) {
                int m = og * 8 + j;
                int nn = (m & 32) + (m & 3) + ((m >> 3) & 3) * 4 + ((m >> 2) & 1) * 16;
                vals[j] = tile[nn][dh];
            }
            *(uint4v*)(out + (size_t)dh * N_ + n0 + og * 8) = *(const uint4v*)vals;
        }
    } else {
        // ---- rms+rope on K cols (vectorized): 8 h-rows/wave, 16B/lane ----
        int wid = (bx - 3072) * 4 + (t >> 6);
        int lane = t & 63;
        int r8 = lane >> 3, e8 = lane & 7;
        int hg = wid & 1;
        int s = (wid >> 1) % 3;
        int row = wid / 6;
        int n = row & (N_ - 1);
        int h = hg * 8 + r8;
        u16* p = QKVB + (size_t)row * 7168 + 1024 + s * 1024 + h * 64 + e8 * 8;
        uint4v v = *(const uint4v*)p;
        float x[8];
#pragma unroll
        for (int j = 0; j < 8; ++j) x[j] = bf2f(((const u16*)&v)[j]);
        float ss = 0.f;
#pragma unroll
        for (int j = 0; j < 8; ++j) ss += x[j] * x[j];
        ss += __shfl_xor(ss, 1, 64);
        ss += __shfl_xor(ss, 2, 64);
        ss += __shfl_xor(ss, 4, 64);
        float rs = rsqrtf(ss * (1.0f / 64.0f) + EPS_);
        const float* ws = w + s * 64 + e8 * 8;
        uint4v pk;
#pragma unroll
        for (int tp = 0; tp < 4; ++tp) {
            int d0 = e8 * 8 + 2 * tp;
            float xn0 = x[2 * tp] * rs * ws[2 * tp];
            float xn1 = x[2 * tp + 1] * rs * ws[2 * tp + 1];
            float inv = exp2f(-(float)d0 * (LOG2_THETA / 64.0f));
            float fr = (float)n * inv;
            float sv, cv;
            __sincosf(fr, &sv, &cv);
            pk[tp] = cvtpk(xn0 * cv - xn1 * sv, xn1 * cv + xn0 * sv);
        }
        *(uint4v*)p = pk;
    }
}

// ---------------- GEMM: C[MxN] = A[MxK] * Bt[NxK]^T ----------------
// T2 swizzle + T1 XCD-chunk swizzle + pointer-SR staging (R7-R15).
// R19 (T4 in its correct regime): 3-buffer LDS rotation with COUNTED vmcnt.
// R6's profile showed the GEMM at 45% combined issue (vs flash's 83%) —
// stall-bound, T4's home regime (rule #23: R4's flash failure was a regime
// mismatch; m248v2 measured 8ph/2ph = 1.10x at exactly K=1024). Loop top waits
// vmcnt(4) (own tile's 4 loads done, next tile's 4 stay in flight across the
// barrier); vmcnt(0) only on the last iteration. Race ledger: stage(kt+2)
// writes buf (kt+2)%3 = (kt-1)%3 whose readers all passed the kt barrier;
// pattern correctness proven in R4 (passed, wrong regime). LDS 48KB -> 3
// blk/CU cap (measured effective residency ~1.5-2, no loss expected).
template <bool OUT_F32>
__global__ __launch_bounds__(256) void k_gemm_bt(
    const u16* __restrict__ A, const u16* __restrict__ Bt, void* __restrict__ Cv,
    int K, int Ncols) {
    int nwg = gridDim.x;
    int chunk = nwg >> 3;                             // nwg % 8 == 0
    int wg = (blockIdx.x & 7) * chunk + (blockIdx.x >> 3);
    int m0 = (wg & 31) * 128, n0 = (wg >> 5) * 128;
    __shared__ u16 As[3][128 * 32];
    __shared__ u16 Bs[3][128 * 32];
    int t = threadIdx.x;
    int w = t >> 6, lane = t & 63, ln = lane & 15, quad = lane >> 4;
    int wm = w & 1, wn = w >> 1;
    float4v acc[4][4] = {};

    // per-thread staged pointers (strength-reduced)
    const u16* gA[2];
    const u16* gB[2];
    int ldsoff[2];
#pragma unroll
    for (int i = 0; i < 2; ++i) {
        int idx = i * 256 + t;
        int row = idx >> 2, kb = idx & 3;
        int csrc = (kb ^ ((row >> 1) & 3)) * 8;       // pre-swizzled source chunk
        gA[i] = A + (size_t)(m0 + row) * K + csrc;
        gB[i] = Bt + (size_t)(n0 + row) * K + csrc;
        ldsoff[i] = idx * 8;
    }

    auto stage = [&](int buf) {
#pragma unroll
        for (int i = 0; i < 2; ++i) {
            __builtin_amdgcn_global_load_lds(
                (const __attribute__((address_space(1))) void*)gA[i],
                (__attribute__((address_space(3))) void*)(As[buf] + ldsoff[i]), 16, 0, 0);
            __builtin_amdgcn_global_load_lds(
                (const __attribute__((address_space(1))) void*)gB[i],
                (__attribute__((address_space(3))) void*)(Bs[buf] + ldsoff[i]), 16, 0, 0);
            gA[i] += 32; gB[i] += 32;
        }
    };

    int nk = K >> 5;                                  // >= 2 for all our shapes
    stage(0);
    stage(1);
    int rchunk = (quad ^ ((ln >> 1) & 3)) * 8;        // loop-invariant read chunk

    for (int kt = 0; kt < nk; ++kt) {
        if (kt + 1 < nk)
            asm volatile("s_waitcnt vmcnt(4)" ::: "memory");   // own tile done; next stays in flight
        else
            asm volatile("s_waitcnt vmcnt(0)" ::: "memory");   // nothing further outstanding
        __syncthreads();
        if (kt + 2 < nk) stage((kt + 2) % 3);
        int buf = kt % 3;
        short8 af[4], bfr[4];
#pragma unroll
        for (int mt = 0; mt < 4; ++mt)
            af[mt] = *(const short8*)(As[buf] + (wm * 64 + mt * 16 + ln) * 32 + rchunk);
#pragma unroll
        for (int nt = 0; nt < 4; ++nt)
            bfr[nt] = *(const short8*)(Bs[buf] + (wn * 64 + nt * 16 + ln) * 32 + rchunk);
#pragma unroll
        for (int mt = 0; mt < 4; ++mt)
#pragma unroll
            for (int nt = 0; nt < 4; ++nt)
                acc[mt][nt] = __builtin_amdgcn_mfma_f32_16x16x32_bf16(
                    af[mt], bfr[nt], acc[mt][nt], 0, 0, 0);
    }
#pragma unroll
    for (int mt = 0; mt < 4; ++mt)
#pragma unroll
        for (int nt = 0; nt < 4; ++nt)
#pragma unroll
            for (int r = 0; r < 4; ++r) {
                int row = m0 + wm * 64 + mt * 16 + quad * 4 + r;
                int col = n0 + wn * 64 + nt * 16 + ln;
                if (OUT_F32)
                    ((float*)Cv)[(size_t)row * Ncols + col] = acc[mt][nt][r];
                else
                    ((u16*)Cv)[(size_t)row * Ncols + col] = f2bf(acc[mt][nt][r]);
            }
}

// ---------------- flash attention v21 (R16/R18 best): setprio regime-split ----------------
// L1 (WIN=1): no setprio (barrier-lockstep waves = m190 regression regime), 32KB
// LDS, 3 blk/CU — measured ~106us. L2 (WIN=2): setprio + two-tile windows (R12's
// barrier halving, occupancy-free at its 2-blk/CU residency). Pointer-SR staging
// everywhere. UNCHANGED this round.
template <int WIN>
__global__ __launch_bounds__(256, WIN == 1 ? 3 : 2) void k_flash(
    const u16* __restrict__ Q, int q_stride,
    const u16* __restrict__ K, const u16* __restrict__ Vt,
    u16* __restrict__ O, u16* __restrict__ Ot,
    int kv_stride, int set_off, size_t o_set_stride,
    const float* __restrict__ wnk) {
    constexpr bool PRIO = (WIN == 2);
    int bh = blockIdx.x;                     // KV-stream on x: XCD L2 locality
    int qt = gridDim.y - 1 - blockIdx.y;     // long blocks first
    int s = blockIdx.z;
    int b = bh >> 4, h = bh & 15;
    int t = threadIdx.x;
    int w = t >> 6, lane = t & 63, ln = lane & 15, quad = lane >> 4;
    int lnx = ln & 7;
    int q0 = qt * 128;
    int qw = q0 + w * 32;

    const u16* Qb  = Q + ((size_t)b * N_) * q_stride + h * 64;
    const u16* Kb  = K + ((size_t)b * N_) * kv_stride + (size_t)s * set_off + h * 64;
    const u16* Vtb = Vt + (size_t)((s * B_ + b) * H_ + h) * (64 * (size_t)N_);

    __shared__ u16 Ks[2][WIN][64][64];       // [win-buf][sub-tile], chunk-XOR swizzled
    __shared__ u16 Vs[2][WIN][64][64];       // dh-major, perm32 keys, swizzled

    short8 ones;
#pragma unroll
    for (int j = 0; j < 8; ++j) ((u16*)&ones)[j] = 0x3F80;

    short8 qf[2][2];
    float mrow[2];                           // per-lane: bound for qrow = qg+ln
    float4v accO[2][4] = {};
    float4v accL[2] = {};
#pragma unroll
    for (int g = 0; g < 2; ++g) {
        int qg = qw + g * 16;
        int tokn = qg + ln;
        short8 raw[2];
#pragma unroll
        for (int f = 0; f < 2; ++f)
            raw[f] = *(const short8*)(Qb + (size_t)tokn * q_stride + f * 32 + quad * 8);
        float qn = 0.f;
#pragma unroll
        for (int f = 0; f < 2; ++f)
#pragma unroll
            for (int j = 0; j < 8; ++j) {
                float v = bf2f(((const u16*)&raw[f])[j]);
                qn += v * v;
            }
        qn += __shfl_xor(qn, 16, 64);
        qn += __shfl_xor(qn, 32, 64);        // lane now has ||q_{qg+ln}||^2
        mrow[g] = sqrtf(qn) * (8.0f * SCL_) * 1.03f + 1e-6f;
        // fused RoPE, folding SCL into Q
#pragma unroll
        for (int f = 0; f < 2; ++f) {
            u16 out8[8];
            int dbase = f * 32 + quad * 8;
#pragma unroll
            for (int tp = 0; tp < 4; ++tp) {
                int d = dbase + 2 * tp;
                float inv = exp2f((float)d * (-LOG2_THETA / 64.0f));
                float fr = (float)tokn * inv;
                float sv, cv;
                __sincosf(fr, &sv, &cv);
                float x0 = bf2f(((const u16*)&raw[f])[2 * tp]);
                float x1 = bf2f(((const u16*)&raw[f])[2 * tp + 1]);
                out8[2 * tp]     = f2bf((x0 * cv - x1 * sv) * SCL_);
                out8[2 * tp + 1] = f2bf((x1 * cv + x0 * sv) * SCL_);
            }
            qf[g][f] = *(const short8*)out8;
        }
    }

    int ntb = 2 * qt + 2;                    // tiles (always even)
    int nwin = ntb / WIN;                    // windows (WIN divides ntb for WIN<=2)

    // per-thread staged pointers (strength-reduced; advance by one tile per sub)
    const u16* kP[2];
    const u16* vP[2];
    int ldsoff[2];                           // element offset within one 64x64 tile
    u16* ldsKbase = &Ks[0][0][0][0];
    u16* ldsVbase = &Vs[0][0][0][0];
#pragma unroll
    for (int i = 0; i < 2; ++i) {
        int idx = i * 256 + t;
        int row = idx >> 3, c = idx & 7;
        int csrc = ((c ^ (row & 7)) * 8);
        kP[i] = Kb + (size_t)row * kv_stride + csrc;
        vP[i] = Vtb + (size_t)row * N_ + csrc;
        ldsoff[i] = row * 64 + c * 8;
    }
    int kAdvance = 64 * kv_stride;

    auto stage = [&](int buf) {
#pragma unroll
        for (int sub = 0; sub < WIN; ++sub) {
            int toff = (buf * WIN + sub) * (64 * 64);
#pragma unroll
            for (int i = 0; i < 2; ++i) {
                __builtin_amdgcn_global_load_lds(
                    (const __attribute__((address_space(1))) void*)kP[i],
                    (__attribute__((address_space(3))) void*)(ldsKbase + toff + ldsoff[i]), 16, 0, 0);
                __builtin_amdgcn_global_load_lds(
                    (const __attribute__((address_space(1))) void*)vP[i],
                    (__attribute__((address_space(3))) void*)(ldsVbase + toff + ldsoff[i]), 16, 0, 0);
                kP[i] += kAdvance;
                vP[i] += 64;
            }
        }
    };

    // one k-tile: QK^T -> exp/pack -> PV (identical math to v13)
    auto compute = [&](int buf, int sub, int k0) {
        short8 kf[4][2];
#pragma unroll
        for (int kt = 0; kt < 4; ++kt) {
            const u16* krow = &Ks[buf][sub][kt * 16 + ln][0];
            kf[kt][0] = *(const short8*)(krow + ((quad ^ lnx) * 8));
            kf[kt][1] = *(const short8*)(krow + (((4 + quad) ^ lnx) * 8));
        }
        short8 pb[2][2];                     // P^T B-fragments [g][32-key chunk]
#pragma unroll
        for (int g = 0; g < 2; ++g) {
            int qg = qw + g * 16;
            // S^T: D[key=quad*4+r][qrow=ln], C-init = -m(qrow)
            float4v st[4];
            if (PRIO) __builtin_amdgcn_s_setprio(1);
#pragma unroll
            for (int kt = 0; kt < 4; ++kt) {
                float4v sa = {-mrow[g], -mrow[g], -mrow[g], -mrow[g]};
                sa = __builtin_amdgcn_mfma_f32_16x16x32_bf16(kf[kt][0], qf[g][0], sa, 0, 0, 0);
                sa = __builtin_amdgcn_mfma_f32_16x16x32_bf16(kf[kt][1], qf[g][1], sa, 0, 0, 0);
                st[kt] = sa;
            }
            if (PRIO) __builtin_amdgcn_s_setprio(0);
            if (k0 + 63 <= qg) {
                // fully unmasked (wave-uniform fast path)
#pragma unroll
                for (int c = 0; c < 2; ++c) {
                    uint4v pk;
#pragma unroll
                    for (int kt2 = 0; kt2 < 2; ++kt2) {
                        pk[kt2 * 2 + 0] = cvtpk(exp2f(st[c * 2 + kt2][0]),
                                                exp2f(st[c * 2 + kt2][1]));
                        pk[kt2 * 2 + 1] = cvtpk(exp2f(st[c * 2 + kt2][2]),
                                                exp2f(st[c * 2 + kt2][3]));
                    }
                    pb[g][c] = *(short8*)&pk;
                }
            } else {
                int qr = qg + ln;            // this lane's q-row
#pragma unroll
                for (int c = 0; c < 2; ++c) {
                    uint4v pk;
#pragma unroll
                    for (int kt2 = 0; kt2 < 2; ++kt2) {
                        int kt = c * 2 + kt2;
                        float e[4];
#pragma unroll
                        for (int r = 0; r < 4; ++r) {
                            int kg = k0 + kt * 16 + quad * 4 + r;
                            float arg = (kg <= qr) ? st[kt][r] : -1e30f;
                            e[r] = exp2f(arg);
                        }
                        pk[kt2 * 2 + 0] = cvtpk(e[0], e[1]);
                        pk[kt2 * 2 + 1] = cvtpk(e[2], e[3]);
                    }
                    pb[g][c] = *(short8*)&pk;
                }
            }
        }
        // O^T += V^T P^T ; l += ones P^T
        if (PRIO) __builtin_amdgcn_s_setprio(1);
#pragma unroll
        for (int dc = 0; dc < 4; ++dc) {
            const u16* vrow = &Vs[buf][sub][dc * 16 + ln][0];
            short8 vf0 = *(const short8*)(vrow + ((quad ^ lnx) * 8));
            short8 vf1 = *(const short8*)(vrow + (((4 + quad) ^ lnx) * 8));
#pragma unroll
            for (int g = 0; g < 2; ++g) {
                accO[g][dc] = __builtin_amdgcn_mfma_f32_16x16x32_bf16(vf0, pb[g][0], accO[g][dc], 0, 0, 0);
                accO[g][dc] = __builtin_amdgcn_mfma_f32_16x16x32_bf16(vf1, pb[g][1], accO[g][dc], 0, 0, 0);
            }
        }
#pragma unroll
        for (int g = 0; g < 2; ++g) {
            accL[g] = __builtin_amdgcn_mfma_f32_16x16x32_bf16(ones, pb[g][0], accL[g], 0, 0, 0);
            accL[g] = __builtin_amdgcn_mfma_f32_16x16x32_bf16(ones, pb[g][1], accL[g], 0, 0, 0);
        }
        if (PRIO) __builtin_amdgcn_s_setprio(0);
    };

    stage(0);

    for (int wv = 0; wv < nwin; ++wv) {
        asm volatile("s_waitcnt vmcnt(0)" ::: "memory");
        __syncthreads();
        if (wv + 1 < nwin) stage((wv + 1) & 1);
        int buf = wv & 1;
        int k0 = wv * (WIN * 64);
        if (k0 > qw + 31) continue;          // whole window beyond causal bound
        compute(buf, 0, k0);                 // tile A
        if (WIN == 2 && k0 + 64 <= qw + 31)  // tile B needed by this wave?
            compute(buf, 1, k0 + 64);
    }

#pragma unroll
    for (int g = 0; g < 2; ++g) {
        float rinv = 1.0f / accL[g][0];      // l for qrow=ln (same in all rows)
        int qg = qw + g * 16;
        int qr = qg + ln;
        if (s == 2) {
            // O^T is already the transposed layout; apply perm32 on qrow for L2's Vt
            u16* Otb = Ot + (size_t)(b * H_ + h) * (64 * (size_t)N_);
            int pos = perm32(qr & (N_ - 1)) + (qr & ~(N_ - 1));
#pragma unroll
            for (int dc = 0; dc < 4; ++dc)
#pragma unroll
                for (int r = 0; r < 4; ++r)
                    Otb[(size_t)(dc * 16 + quad * 4 + r) * N_ + pos] =
                        f2bf(accO[g][dc][r] * rinv);
        } else if (wnk && s == 1) {
            // fused nested-K rmsnorm + RoPE (replaces the rope-L2 kernel)
            u16* Ob = O + o_set_stride + ((size_t)b * N_) * DI_ + h * 64;
            float o[4][4];
            float ss = 0.f;
#pragma unroll
            for (int dc = 0; dc < 4; ++dc)
#pragma unroll
                for (int r = 0; r < 4; ++r) {
                    float x = accO[g][dc][r] * rinv;
                    o[dc][r] = x;
                    ss += x * x;
                }
            ss += __shfl_xor(ss, 16, 64);
            ss += __shfl_xor(ss, 32, 64);    // sum over the row's 4 quads
            float rs2 = rsqrtf(ss * (1.0f / 64.0f) + EPS_);
#pragma unroll
            for (int dc = 0; dc < 4; ++dc) {
                uint2 pk;
#pragma unroll
                for (int rp = 0; rp < 2; ++rp) {
                    int d0 = dc * 16 + quad * 4 + 2 * rp;
                    float x0 = o[dc][2 * rp]     * rs2 * wnk[d0];
                    float x1 = o[dc][2 * rp + 1] * rs2 * wnk[d0 + 1];
                    float inv = exp2f(-(float)d0 * (LOG2_THETA / 64.0f));
                    float fr = (float)qr * inv;
                    float sv, cv;
                    __sincosf(fr, &sv, &cv);
                    unsigned int u = cvtpk(x0 * cv - x1 * sv, x1 * cv + x0 * sv);
                    if (rp == 0) pk.x = u; else pk.y = u;
                }
                *(uint2*)(Ob + (size_t)qr * DI_ + dc * 16 + quad * 4) = pk;
            }
        } else {
            u16* Ob = O + (size_t)s * o_set_stride + ((size_t)b * N_) * DI_ + h * 64;
#pragma unroll
            for (int dc = 0; dc < 4; ++dc) {
                uint2 pk;
                pk.x = cvtpk(accO[g][dc][0] * rinv, accO[g][dc][1] * rinv);
                pk.y = cvtpk(accO[g][dc][2] * rinv, accO[g][dc][3] * rinv);
                *(uint2*)(Ob + (size_t)qr * DI_ + dc * 16 + quad * 4) = pk;
            }
        }
    }
}

extern "C" void kernel_launch(void* const* d_in, const int* in_sizes, int n_in,
                              void* d_out, int out_size, void* d_ws, size_t ws_size,
                              hipStream_t stream) {
    const float* tok     = (const float*)d_in[0];
    const float* w_norm  = (const float*)d_in[1];
    const float* w_q     = (const float*)d_in[2];
    const float* w_k     = (const float*)d_in[3];
    const float* w_v     = (const float*)d_in[4];
    const float* w_keyn  = (const float*)d_in[5];
    const float* w_nestk = (const float*)d_in[6];
    const float* w_o     = (const float*)d_in[7];

    char* ws = (char*)d_ws;
    const size_t MB = 1024 * 1024;
    u16* QKVB  = (u16*)(ws + 0 * MB);    // [0,56)   4096 x 7168 bf16
    u16* VtB   = (u16*)(ws + 56 * MB);   // [56,80)
    u16* NQKV  = (u16*)(ws + 80 * MB);   // [80,96)  sets 0,1 token-major (written by L1)
    u16* WQKVT = (u16*)(ws + 80 * MB);   // [80,94)  dead before L1 writes NQKV
    u16* NVt   = (u16*)(ws + 96 * MB);   // [96,104) set 2 transposed (written by L1)
    u16* XN    = (u16*)(ws + 96 * MB);   // [96,104) dead after QKV GEMM
    u16* OUT2  = (u16*)(ws + 104 * MB);  // [104,112) written by L2
    u16* WOT   = (u16*)(ws + 80 * MB);   // [80,82)  re-created after L2 (NQKV dead)

    const size_t SET = (size_t)B_ * N_ * DI_;

    // merged preprocessing: qkv transpose (7168 blocks) + rmsnorm (4096 blocks)
    k_pre<<<7168 + 4096, 256, 0, stream>>>(w_q, w_k, w_v, WQKVT, tok, w_norm, XN);

    // QKV GEMM: 1D swizzled grid (32 m-tiles x 56 n-tiles = 1792, %8==0)
    k_gemm_bt<false><<<1792, 256, 0, stream>>>(XN, WQKVT, QKVB, 1024, 7168);

    // merged post-GEMM: V transpose (3072 blocks) + K rms/rope (6144 blocks)
    k_post1<<<3072 + 6144, 256, 0, stream>>>(QKVB, VtB, w_keyn);

    // L1 flash (WIN=1, no setprio) with fused nested-K rms/rope on s==1
    k_flash<1><<<dim3(B_ * H_, N_ / 128, 3), 256, 0, stream>>>(
        QKVB, 7168, QKVB + 1024, VtB, NQKV, NVt, 7168, 1024, SET, w_nestk);

    // L2 flash (WIN=2 + setprio)
    k_flash<2><<<dim3(B_ * H_, N_ / 128, 1), 256, 0, stream>>>(
        NQKV, 1024, NQKV + SET, NVt, OUT2, NVt /*unused*/, 1024, 0, 0, nullptr);

    k_transpose<<<dim3(32, 32), dim3(32, 8), 0, stream>>>(w_o, WOT, 1024, 1024);
    // out-GEMM: 1D swizzled grid (32 m-tiles x 8 n-tiles = 256, %8==0)
    k_gemm_bt<true><<<256, 256, 0, stream>>>(OUT2, WOT, (float*)d_out, 1024, 1024);
}

// Round 20
// 356.024 us; speedup vs baseline: 1.0067x; 1.0067x over previous
//
#include <hip/hip_runtime.h>
#include <hip/hip_bf16.h>
#include <stdint.h>

typedef unsigned short u16;
typedef __attribute__((ext_vector_type(8))) short short8;
typedef __attribute__((ext_vector_type(4))) float float4v;
typedef __attribute__((ext_vector_type(4))) unsigned int uint4v;

#define B_    2
#define N_    2048
#define DIM_  1024
#define H_    16
#define DH_   64
#define DI_   1024
#define EPS_  1.1920928955078125e-07f
#define LOG2_THETA 13.287712379549449f
#define SCL_  0.18033688011112042f   // (1/sqrt(64)) * log2(e)

__device__ __forceinline__ float bf2f(u16 u) {
    union { unsigned int i; float f; } v; v.i = ((unsigned int)u) << 16; return v.f;
}
__device__ __forceinline__ u16 f2bf(float f) {
    union { float f; unsigned int i; } v; v.f = f;
    unsigned int r = v.i + 0x7fff + ((v.i >> 16) & 1);
    return (u16)(r >> 16);
}
// single-instruction packed f32->bf16 (RNE)
__device__ __forceinline__ unsigned int cvtpk(float a, float b) {
    unsigned int r;
    asm("v_cvt_pk_bf16_f32 %0, %1, %2" : "=v"(r) : "v"(a), "v"(b));
    return r;
}
// key permutation within a 32-key group (matches S^T reg layout -> B-operand)
__device__ __forceinline__ int perm32(int n) {
    return (n & ~31) + (((n >> 2) & 3) * 8) + (((n >> 4) & 1) * 4) + (n & 3);
}

// ---------------- merged preprocessing: qkv weight transpose + token RMSNorm ----------------
__global__ __launch_bounds__(256) void k_pre(
    const float* __restrict__ w_q, const float* __restrict__ w_k,
    const float* __restrict__ w_v, u16* __restrict__ dstW,
    const float* __restrict__ tok, const float* __restrict__ w_norm,
    u16* __restrict__ xn) {
    int bx = blockIdx.x;
    int t = threadIdx.x;
    __shared__ float tile[32][33];
    __shared__ float red[4];
    if (bx < 7168) {
        // ---- transpose_qkv tile (c-tile = bx%224, k-tile = bx/224) ----
        int c0 = (bx % 224) * 32, k0 = (bx / 224) * 32;
        const float* src; int sN, sc0;
        if (c0 < 1024)      { src = w_q; sN = 1024; sc0 = c0; }
        else if (c0 < 4096) { src = w_k; sN = 3072; sc0 = c0 - 1024; }
        else                { src = w_v; sN = 3072; sc0 = c0 - 4096; }
        int tx = t & 31, ty = t >> 5;
#pragma unroll
        for (int i = 0; i < 4; ++i)
            tile[ty + 8 * i][tx] = src[(size_t)(k0 + ty + 8 * i) * sN + sc0 + tx];
        __syncthreads();
#pragma unroll
        for (int i = 0; i < 4; ++i)
            dstW[(size_t)(c0 + ty + 8 * i) * 1024 + k0 + tx] = f2bf(tile[tx][ty + 8 * i]);
    } else {
        // ---- rmsnorm_x row = bx - 7168 (vectorized) ----
        int row = bx - 7168;
        const float* tr = tok + (size_t)row * DIM_ + t * 4;
        float4v v = *(const float4v*)tr;
        float ss = v[0] * v[0] + v[1] * v[1] + v[2] * v[2] + v[3] * v[3];
#pragma unroll
        for (int o = 32; o; o >>= 1) ss += __shfl_xor(ss, o, 64);
        if ((t & 63) == 0) red[t >> 6] = ss;
        __syncthreads();
        ss = red[0] + red[1] + red[2] + red[3];
        float rs = rsqrtf(ss * (1.0f / DIM_) + EPS_);
        const float* wp = w_norm + t * 4;
        uint2 pk;
        pk.x = cvtpk(v[0] * rs * wp[0], v[1] * rs * wp[1]);
        pk.y = cvtpk(v[2] * rs * wp[2], v[3] * rs * wp[3]);
        *(uint2*)(xn + (size_t)row * DIM_ + t * 4) = pk;
    }
}

// ---------------- single weight transpose (K x N fp32) -> (N x K bf16) ----------------
__global__ __launch_bounds__(256) void k_transpose(
    const float* __restrict__ src, u16* __restrict__ dst, int K, int N) {
    __shared__ float tile[32][33];
    int n0 = blockIdx.x * 32, k0 = blockIdx.y * 32;
    int tx = threadIdx.x, ty = threadIdx.y;  // 32 x 8
#pragma unroll
    for (int i = 0; i < 4; ++i)
        tile[ty + 8 * i][tx] = src[(size_t)(k0 + ty + 8 * i) * N + n0 + tx];
    __syncthreads();
#pragma unroll
    for (int i = 0; i < 4; ++i)
        dst[(size_t)(n0 + ty + 8 * i) * K + k0 + tx] = f2bf(tile[tx][ty + 8 * i]);
}

// ------- merged post-GEMM: V transpose + K rms+rope (independent col ranges) -------
__global__ __launch_bounds__(256) void k_post1(
    u16* __restrict__ QKVB, u16* __restrict__ Vt, const float* __restrict__ w) {
    int bx = blockIdx.x;
    int t = threadIdx.x;
    __shared__ u16 tile[64][72];
    if (bx < 3072) {
        // ---- transpose_v (vectorized): y = bx>>5, n-tile = bx&31 ----
        int y = bx >> 5;
        int s = y >> 5;
        int b = (y >> 4) & 1;
        int h = y & 15;
        int n0 = (bx & 31) * 64;
#pragma unroll
        for (int i = 0; i < 2; ++i) {
            int idx = i * 256 + t;
            int row = idx >> 3, c = idx & 7;
            uint4v v = *(const uint4v*)(QKVB + ((size_t)(b * N_) + n0 + row) * 7168
                                            + 4096 + s * 1024 + h * 64 + c * 8);
            *(uint4v*)&tile[row][c * 8] = v;
        }
        __syncthreads();
        u16* out = Vt + (size_t)y * 64 * N_;
#pragma unroll
        for (int i = 0; i < 2; ++i) {
            int idx = i * 256 + t;
            int dh = idx >> 3, og = idx & 7;
            u16 vals[8];
#pragma unroll
            for (int j = 0; j < 8; ++j) {
                int m = og * 8 + j;
                int nn = (m & 32) + (m & 3) + ((m >> 3) & 3) * 4 + ((m >> 2) & 1) * 16;
                vals[j] = tile[nn][dh];
            }
            *(uint4v*)(out + (size_t)dh * N_ + n0 + og * 8) = *(const uint4v*)vals;
        }
    } else {
        // ---- rms+rope on K cols (vectorized): 8 h-rows/wave, 16B/lane ----
        int wid = (bx - 3072) * 4 + (t >> 6);
        int lane = t & 63;
        int r8 = lane >> 3, e8 = lane & 7;
        int hg = wid & 1;
        int s = (wid >> 1) % 3;
        int row = wid / 6;
        int n = row & (N_ - 1);
        int h = hg * 8 + r8;
        u16* p = QKVB + (size_t)row * 7168 + 1024 + s * 1024 + h * 64 + e8 * 8;
        uint4v v = *(const uint4v*)p;
        float x[8];
#pragma unroll
        for (int j = 0; j < 8; ++j) x[j] = bf2f(((const u16*)&v)[j]);
        float ss = 0.f;
#pragma unroll
        for (int j = 0; j < 8; ++j) ss += x[j] * x[j];
        ss += __shfl_xor(ss, 1, 64);
        ss += __shfl_xor(ss, 2, 64);
        ss += __shfl_xor(ss, 4, 64);
        float rs = rsqrtf(ss * (1.0f / 64.0f) + EPS_);
        const float* ws = w + s * 64 + e8 * 8;
        uint4v pk;
#pragma unroll
        for (int tp = 0; tp < 4; ++tp) {
            int d0 = e8 * 8 + 2 * tp;
            float xn0 = x[2 * tp] * rs * ws[2 * tp];
            float xn1 = x[2 * tp + 1] * rs * ws[2 * tp + 1];
            float inv = exp2f(-(float)d0 * (LOG2_THETA / 64.0f));
            float fr = (float)n * inv;
            float sv, cv;
            __sincosf(fr, &sv, &cv);
            pk[tp] = cvtpk(xn0 * cv - xn1 * sv, xn1 * cv + xn0 * sv);
        }
        *(uint4v*)p = pk;
    }
}

// ---------------- GEMM: C[MxN] = A[MxK] * Bt[NxK]^T ----------------
// Pipelined double-buffer + T2 swizzle + T1 XCD-chunk swizzle + pointer-SR
// staging (R7-R15). Conflicts ~0. setprio OFF (m190: hurts lockstep waves).
// R19's counted-vmcnt 3-buffer variant was flat (+1.6us) — reverted to the
// R18-measured-best 2-buffer vmcnt(0) schedule.
template <bool OUT_F32>
__global__ __launch_bounds__(256) void k_gemm_bt(
    const u16* __restrict__ A, const u16* __restrict__ Bt, void* __restrict__ Cv,
    int K, int Ncols) {
    int nwg = gridDim.x;
    int chunk = nwg >> 3;                             // nwg % 8 == 0
    int wg = (blockIdx.x & 7) * chunk + (blockIdx.x >> 3);
    int m0 = (wg & 31) * 128, n0 = (wg >> 5) * 128;
    __shared__ u16 As[2][128 * 32];
    __shared__ u16 Bs[2][128 * 32];
    int t = threadIdx.x;
    int w = t >> 6, lane = t & 63, ln = lane & 15, quad = lane >> 4;
    int wm = w & 1, wn = w >> 1;
    float4v acc[4][4] = {};

    // per-thread staged pointers (strength-reduced)
    const u16* gA[2];
    const u16* gB[2];
    int ldsoff[2];
#pragma unroll
    for (int i = 0; i < 2; ++i) {
        int idx = i * 256 + t;
        int row = idx >> 2, kb = idx & 3;
        int csrc = (kb ^ ((row >> 1) & 3)) * 8;       // pre-swizzled source chunk
        gA[i] = A + (size_t)(m0 + row) * K + csrc;
        gB[i] = Bt + (size_t)(n0 + row) * K + csrc;
        ldsoff[i] = idx * 8;
    }

    auto stage = [&](int buf) {
#pragma unroll
        for (int i = 0; i < 2; ++i) {
            __builtin_amdgcn_global_load_lds(
                (const __attribute__((address_space(1))) void*)gA[i],
                (__attribute__((address_space(3))) void*)(As[buf] + ldsoff[i]), 16, 0, 0);
            __builtin_amdgcn_global_load_lds(
                (const __attribute__((address_space(1))) void*)gB[i],
                (__attribute__((address_space(3))) void*)(Bs[buf] + ldsoff[i]), 16, 0, 0);
            gA[i] += 32; gB[i] += 32;
        }
    };

    int nk = K >> 5;
    stage(0);
    int rchunk = (quad ^ ((ln >> 1) & 3)) * 8;        // loop-invariant read chunk

    for (int kt = 0; kt < nk; ++kt) {
        asm volatile("s_waitcnt vmcnt(0)" ::: "memory");
        __syncthreads();
        if (kt + 1 < nk) stage((kt + 1) & 1);
        int buf = kt & 1;
        short8 af[4], bfr[4];
#pragma unroll
        for (int mt = 0; mt < 4; ++mt)
            af[mt] = *(const short8*)(As[buf] + (wm * 64 + mt * 16 + ln) * 32 + rchunk);
#pragma unroll
        for (int nt = 0; nt < 4; ++nt)
            bfr[nt] = *(const short8*)(Bs[buf] + (wn * 64 + nt * 16 + ln) * 32 + rchunk);
#pragma unroll
        for (int mt = 0; mt < 4; ++mt)
#pragma unroll
            for (int nt = 0; nt < 4; ++nt)
                acc[mt][nt] = __builtin_amdgcn_mfma_f32_16x16x32_bf16(
                    af[mt], bfr[nt], acc[mt][nt], 0, 0, 0);
    }
#pragma unroll
    for (int mt = 0; mt < 4; ++mt)
#pragma unroll
        for (int nt = 0; nt < 4; ++nt)
#pragma unroll
            for (int r = 0; r < 4; ++r) {
                int row = m0 + wm * 64 + mt * 16 + quad * 4 + r;
                int col = n0 + wn * 64 + nt * 16 + ln;
                if (OUT_F32)
                    ((float*)Cv)[(size_t)row * Ncols + col] = acc[mt][nt][r];
                else
                    ((u16*)Cv)[(size_t)row * Ncols + col] = f2bf(acc[mt][nt][r]);
            }
}

// ---------------- flash attention v21 (R16/R18 best): setprio regime-split ----------------
// L1 (WIN=1): no setprio (barrier-lockstep waves = m190 regression regime), 32KB
// LDS, 3 blk/CU — measured ~106us. L2 (WIN=2): setprio + two-tile windows (R12's
// barrier halving, occupancy-free at its 2-blk/CU residency). Pointer-SR staging
// everywhere.
template <int WIN>
__global__ __launch_bounds__(256, WIN == 1 ? 3 : 2) void k_flash(
    const u16* __restrict__ Q, int q_stride,
    const u16* __restrict__ K, const u16* __restrict__ Vt,
    u16* __restrict__ O, u16* __restrict__ Ot,
    int kv_stride, int set_off, size_t o_set_stride,
    const float* __restrict__ wnk) {
    constexpr bool PRIO = (WIN == 2);
    int bh = blockIdx.x;                     // KV-stream on x: XCD L2 locality
    int qt = gridDim.y - 1 - blockIdx.y;     // long blocks first
    int s = blockIdx.z;
    int b = bh >> 4, h = bh & 15;
    int t = threadIdx.x;
    int w = t >> 6, lane = t & 63, ln = lane & 15, quad = lane >> 4;
    int lnx = ln & 7;
    int q0 = qt * 128;
    int qw = q0 + w * 32;

    const u16* Qb  = Q + ((size_t)b * N_) * q_stride + h * 64;
    const u16* Kb  = K + ((size_t)b * N_) * kv_stride + (size_t)s * set_off + h * 64;
    const u16* Vtb = Vt + (size_t)((s * B_ + b) * H_ + h) * (64 * (size_t)N_);

    __shared__ u16 Ks[2][WIN][64][64];       // [win-buf][sub-tile], chunk-XOR swizzled
    __shared__ u16 Vs[2][WIN][64][64];       // dh-major, perm32 keys, swizzled

    short8 ones;
#pragma unroll
    for (int j = 0; j < 8; ++j) ((u16*)&ones)[j] = 0x3F80;

    short8 qf[2][2];
    float mrow[2];                           // per-lane: bound for qrow = qg+ln
    float4v accO[2][4] = {};
    float4v accL[2] = {};
#pragma unroll
    for (int g = 0; g < 2; ++g) {
        int qg = qw + g * 16;
        int tokn = qg + ln;
        short8 raw[2];
#pragma unroll
        for (int f = 0; f < 2; ++f)
            raw[f] = *(const short8*)(Qb + (size_t)tokn * q_stride + f * 32 + quad * 8);
        float qn = 0.f;
#pragma unroll
        for (int f = 0; f < 2; ++f)
#pragma unroll
            for (int j = 0; j < 8; ++j) {
                float v = bf2f(((const u16*)&raw[f])[j]);
                qn += v * v;
            }
        qn += __shfl_xor(qn, 16, 64);
        qn += __shfl_xor(qn, 32, 64);        // lane now has ||q_{qg+ln}||^2
        mrow[g] = sqrtf(qn) * (8.0f * SCL_) * 1.03f + 1e-6f;
        // fused RoPE, folding SCL into Q
#pragma unroll
        for (int f = 0; f < 2; ++f) {
            u16 out8[8];
            int dbase = f * 32 + quad * 8;
#pragma unroll
            for (int tp = 0; tp < 4; ++tp) {
                int d = dbase + 2 * tp;
                float inv = exp2f((float)d * (-LOG2_THETA / 64.0f));
                float fr = (float)tokn * inv;
                float sv, cv;
                __sincosf(fr, &sv, &cv);
                float x0 = bf2f(((const u16*)&raw[f])[2 * tp]);
                float x1 = bf2f(((const u16*)&raw[f])[2 * tp + 1]);
                out8[2 * tp]     = f2bf((x0 * cv - x1 * sv) * SCL_);
                out8[2 * tp + 1] = f2bf((x1 * cv + x0 * sv) * SCL_);
            }
            qf[g][f] = *(const short8*)out8;
        }
    }

    int ntb = 2 * qt + 2;                    // tiles (always even)
    int nwin = ntb / WIN;                    // windows (WIN divides ntb for WIN<=2)

    // per-thread staged pointers (strength-reduced; advance by one tile per sub)
    const u16* kP[2];
    const u16* vP[2];
    int ldsoff[2];                           // element offset within one 64x64 tile
    u16* ldsKbase = &Ks[0][0][0][0];
    u16* ldsVbase = &Vs[0][0][0][0];
#pragma unroll
    for (int i = 0; i < 2; ++i) {
        int idx = i * 256 + t;
        int row = idx >> 3, c = idx & 7;
        int csrc = ((c ^ (row & 7)) * 8);
        kP[i] = Kb + (size_t)row * kv_stride + csrc;
        vP[i] = Vtb + (size_t)row * N_ + csrc;
        ldsoff[i] = row * 64 + c * 8;
    }
    int kAdvance = 64 * kv_stride;

    auto stage = [&](int buf) {
#pragma unroll
        for (int sub = 0; sub < WIN; ++sub) {
            int toff = (buf * WIN + sub) * (64 * 64);
#pragma unroll
            for (int i = 0; i < 2; ++i) {
                __builtin_amdgcn_global_load_lds(
                    (const __attribute__((address_space(1))) void*)kP[i],
                    (__attribute__((address_space(3))) void*)(ldsKbase + toff + ldsoff[i]), 16, 0, 0);
                __builtin_amdgcn_global_load_lds(
                    (const __attribute__((address_space(1))) void*)vP[i],
                    (__attribute__((address_space(3))) void*)(ldsVbase + toff + ldsoff[i]), 16, 0, 0);
                kP[i] += kAdvance;
                vP[i] += 64;
            }
        }
    };

    // one k-tile: QK^T -> exp/pack -> PV (identical math to v13)
    auto compute = [&](int buf, int sub, int k0) {
        short8 kf[4][2];
#pragma unroll
        for (int kt = 0; kt < 4; ++kt) {
            const u16* krow = &Ks[buf][sub][kt * 16 + ln][0];
            kf[kt][0] = *(const short8*)(krow + ((quad ^ lnx) * 8));
            kf[kt][1] = *(const short8*)(krow + (((4 + quad) ^ lnx) * 8));
        }
        short8 pb[2][2];                     // P^T B-fragments [g][32-key chunk]
#pragma unroll
        for (int g = 0; g < 2; ++g) {
            int qg = qw + g * 16;
            // S^T: D[key=quad*4+r][qrow=ln], C-init = -m(qrow)
            float4v st[4];
            if (PRIO) __builtin_amdgcn_s_setprio(1);
#pragma unroll
            for (int kt = 0; kt < 4; ++kt) {
                float4v sa = {-mrow[g], -mrow[g], -mrow[g], -mrow[g]};
                sa = __builtin_amdgcn_mfma_f32_16x16x32_bf16(kf[kt][0], qf[g][0], sa, 0, 0, 0);
                sa = __builtin_amdgcn_mfma_f32_16x16x32_bf16(kf[kt][1], qf[g][1], sa, 0, 0, 0);
                st[kt] = sa;
            }
            if (PRIO) __builtin_amdgcn_s_setprio(0);
            if (k0 + 63 <= qg) {
                // fully unmasked (wave-uniform fast path)
#pragma unroll
                for (int c = 0; c < 2; ++c) {
                    uint4v pk;
#pragma unroll
                    for (int kt2 = 0; kt2 < 2; ++kt2) {
                        pk[kt2 * 2 + 0] = cvtpk(exp2f(st[c * 2 + kt2][0]),
                                                exp2f(st[c * 2 + kt2][1]));
                        pk[kt2 * 2 + 1] = cvtpk(exp2f(st[c * 2 + kt2][2]),
                                                exp2f(st[c * 2 + kt2][3]));
                    }
                    pb[g][c] = *(short8*)&pk;
                }
            } else {
                int qr = qg + ln;            // this lane's q-row
#pragma unroll
                for (int c = 0; c < 2; ++c) {
                    uint4v pk;
#pragma unroll
                    for (int kt2 = 0; kt2 < 2; ++kt2) {
                        int kt = c * 2 + kt2;
                        float e[4];
#pragma unroll
                        for (int r = 0; r < 4; ++r) {
                            int kg = k0 + kt * 16 + quad * 4 + r;
                            float arg = (kg <= qr) ? st[kt][r] : -1e30f;
                            e[r] = exp2f(arg);
                        }
                        pk[kt2 * 2 + 0] = cvtpk(e[0], e[1]);
                        pk[kt2 * 2 + 1] = cvtpk(e[2], e[3]);
                    }
                    pb[g][c] = *(short8*)&pk;
                }
            }
        }
        // O^T += V^T P^T ; l += ones P^T
        if (PRIO) __builtin_amdgcn_s_setprio(1);
#pragma unroll
        for (int dc = 0; dc < 4; ++dc) {
            const u16* vrow = &Vs[buf][sub][dc * 16 + ln][0];
            short8 vf0 = *(const short8*)(vrow + ((quad ^ lnx) * 8));
            short8 vf1 = *(const short8*)(vrow + (((4 + quad) ^ lnx) * 8));
#pragma unroll
            for (int g = 0; g < 2; ++g) {
                accO[g][dc] = __builtin_amdgcn_mfma_f32_16x16x32_bf16(vf0, pb[g][0], accO[g][dc], 0, 0, 0);
                accO[g][dc] = __builtin_amdgcn_mfma_f32_16x16x32_bf16(vf1, pb[g][1], accO[g][dc], 0, 0, 0);
            }
        }
#pragma unroll
        for (int g = 0; g < 2; ++g) {
            accL[g] = __builtin_amdgcn_mfma_f32_16x16x32_bf16(ones, pb[g][0], accL[g], 0, 0, 0);
            accL[g] = __builtin_amdgcn_mfma_f32_16x16x32_bf16(ones, pb[g][1], accL[g], 0, 0, 0);
        }
        if (PRIO) __builtin_amdgcn_s_setprio(0);
    };

    stage(0);

    for (int wv = 0; wv < nwin; ++wv) {
        asm volatile("s_waitcnt vmcnt(0)" ::: "memory");
        __syncthreads();
        if (wv + 1 < nwin) stage((wv + 1) & 1);
        int buf = wv & 1;
        int k0 = wv * (WIN * 64);
        if (k0 > qw + 31) continue;          // whole window beyond causal bound
        compute(buf, 0, k0);                 // tile A
        if (WIN == 2 && k0 + 64 <= qw + 31)  // tile B needed by this wave?
            compute(buf, 1, k0 + 64);
    }

#pragma unroll
    for (int g = 0; g < 2; ++g) {
        float rinv = 1.0f / accL[g][0];      // l for qrow=ln (same in all rows)
        int qg = qw + g * 16;
        int qr = qg + ln;
        if (s == 2) {
            // O^T is already the transposed layout; apply perm32 on qrow for L2's Vt
            u16* Otb = Ot + (size_t)(b * H_ + h) * (64 * (size_t)N_);
            int pos = perm32(qr & (N_ - 1)) + (qr & ~(N_ - 1));
#pragma unroll
            for (int dc = 0; dc < 4; ++dc)
#pragma unroll
                for (int r = 0; r < 4; ++r)
                    Otb[(size_t)(dc * 16 + quad * 4 + r) * N_ + pos] =
                        f2bf(accO[g][dc][r] * rinv);
        } else if (wnk && s == 1) {
            // fused nested-K rmsnorm + RoPE (replaces the rope-L2 kernel)
            u16* Ob = O + o_set_stride + ((size_t)b * N_) * DI_ + h * 64;
            float o[4][4];
            float ss = 0.f;
#pragma unroll
            for (int dc = 0; dc < 4; ++dc)
#pragma unroll
                for (int r = 0; r < 4; ++r) {
                    float x = accO[g][dc][r] * rinv;
                    o[dc][r] = x;
                    ss += x * x;
                }
            ss += __shfl_xor(ss, 16, 64);
            ss += __shfl_xor(ss, 32, 64);    // sum over the row's 4 quads
            float rs2 = rsqrtf(ss * (1.0f / 64.0f) + EPS_);
#pragma unroll
            for (int dc = 0; dc < 4; ++dc) {
                uint2 pk;
#pragma unroll
                for (int rp = 0; rp < 2; ++rp) {
                    int d0 = dc * 16 + quad * 4 + 2 * rp;
                    float x0 = o[dc][2 * rp]     * rs2 * wnk[d0];
                    float x1 = o[dc][2 * rp + 1] * rs2 * wnk[d0 + 1];
                    float inv = exp2f(-(float)d0 * (LOG2_THETA / 64.0f));
                    float fr = (float)qr * inv;
                    float sv, cv;
                    __sincosf(fr, &sv, &cv);
                    unsigned int u = cvtpk(x0 * cv - x1 * sv, x1 * cv + x0 * sv);
                    if (rp == 0) pk.x = u; else pk.y = u;
                }
                *(uint2*)(Ob + (size_t)qr * DI_ + dc * 16 + quad * 4) = pk;
            }
        } else {
            u16* Ob = O + (size_t)s * o_set_stride + ((size_t)b * N_) * DI_ + h * 64;
#pragma unroll
            for (int dc = 0; dc < 4; ++dc) {
                uint2 pk;
                pk.x = cvtpk(accO[g][dc][0] * rinv, accO[g][dc][1] * rinv);
                pk.y = cvtpk(accO[g][dc][2] * rinv, accO[g][dc][3] * rinv);
                *(uint2*)(Ob + (size_t)qr * DI_ + dc * 16 + quad * 4) = pk;
            }
        }
    }
}

extern "C" void kernel_launch(void* const* d_in, const int* in_sizes, int n_in,
                              void* d_out, int out_size, void* d_ws, size_t ws_size,
                              hipStream_t stream) {
    const float* tok     = (const float*)d_in[0];
    const float* w_norm  = (const float*)d_in[1];
    const float* w_q     = (const float*)d_in[2];
    const float* w_k     = (const float*)d_in[3];
    const float* w_v     = (const float*)d_in[4];
    const float* w_keyn  = (const float*)d_in[5];
    const float* w_nestk = (const float*)d_in[6];
    const float* w_o     = (const float*)d_in[7];

    char* ws = (char*)d_ws;
    const size_t MB = 1024 * 1024;
    u16* QKVB  = (u16*)(ws + 0 * MB);    // [0,56)   4096 x 7168 bf16
    u16* VtB   = (u16*)(ws + 56 * MB);   // [56,80)
    u16* NQKV  = (u16*)(ws + 80 * MB);   // [80,96)  sets 0,1 token-major (written by L1)
    u16* WQKVT = (u16*)(ws + 80 * MB);   // [80,94)  dead before L1 writes NQKV
    u16* NVt   = (u16*)(ws + 96 * MB);   // [96,104) set 2 transposed (written by L1)
    u16* XN    = (u16*)(ws + 96 * MB);   // [96,104) dead after QKV GEMM
    u16* OUT2  = (u16*)(ws + 104 * MB);  // [104,112) written by L2
    u16* WOT   = (u16*)(ws + 80 * MB);   // [80,82)  re-created after L2 (NQKV dead)

    const size_t SET = (size_t)B_ * N_ * DI_;

    // merged preprocessing: qkv transpose (7168 blocks) + rmsnorm (4096 blocks)
    k_pre<<<7168 + 4096, 256, 0, stream>>>(w_q, w_k, w_v, WQKVT, tok, w_norm, XN);

    // QKV GEMM: 1D swizzled grid (32 m-tiles x 56 n-tiles = 1792, %8==0)
    k_gemm_bt<false><<<1792, 256, 0, stream>>>(XN, WQKVT, QKVB, 1024, 7168);

    // merged post-GEMM: V transpose (3072 blocks) + K rms/rope (6144 blocks)
    k_post1<<<3072 + 6144, 256, 0, stream>>>(QKVB, VtB, w_keyn);

    // L1 flash (WIN=1, no setprio) with fused nested-K rms/rope on s==1
    k_flash<1><<<dim3(B_ * H_, N_ / 128, 3), 256, 0, stream>>>(
        QKVB, 7168, QKVB + 1024, VtB, NQKV, NVt, 7168, 1024, SET, w_nestk);

    // L2 flash (WIN=2 + setprio)
    k_flash<2><<<dim3(B_ * H_, N_ / 128, 1), 256, 0, stream>>>(
        NQKV, 1024, NQKV + SET, NVt, OUT2, NVt /*unused*/, 1024, 0, 0, nullptr);

    k_transpose<<<dim3(32, 32), dim3(32, 8), 0, stream>>>(w_o, WOT, 1024, 1024);
    // out-GEMM: 1D swizzled grid (32 m-tiles x 8 n-tiles = 256, %8==0)
    k_gemm_bt<true><<<256, 256, 0, stream>>>(OUT2, WOT, (float*)d_out, 1024, 1024);
}